// Round 1
// baseline (565.732 us; speedup 1.0000x reference)
//
#include <hip/hip_runtime.h>
#include <hip/hip_bf16.h>

#define Bn 128
#define Hd 512
#define Nn 1024

typedef __attribute__((ext_vector_type(8))) short short8;
typedef __attribute__((ext_vector_type(4))) float f32x4;

#define GLOAD_LDS16(gptr, lptr)                                                     \
    __builtin_amdgcn_global_load_lds(                                               \
        (const __attribute__((address_space(1))) void*)(gptr),                      \
        (__attribute__((address_space(3))) void*)(lptr), 16, 0, 0)

__device__ __forceinline__ float bf2f(unsigned u) {
    unsigned v = u << 16;
    float f;
    __builtin_memcpy(&f, &v, 4);
    return f;
}

__device__ __forceinline__ unsigned short f2bf(float f) {
    unsigned x;
    __builtin_memcpy(&x, &f, 4);
    unsigned r = x + 0x7fffu + ((x >> 16) & 1u);
    return (unsigned short)(r >> 16);
}

__device__ __forceinline__ float wave_sum(float v) {
    v += __shfl_xor(v, 32);
    v += __shfl_xor(v, 16);
    v += __shfl_xor(v, 8);
    v += __shfl_xor(v, 4);
    v += __shfl_xor(v, 2);
    v += __shfl_xor(v, 1);
    return v;
}

__device__ __forceinline__ float tanh_fast(float x) {
    float e = __expf(2.0f * x);
    return 1.0f - 2.0f * __builtin_amdgcn_rcpf(e + 1.0f);
}

// ---------------------------------------------------------------------------
// K0a: Wb[h][k] = bf16(attn_W[h][k]), k in [0,512)
// ---------------------------------------------------------------------------
__global__ void convert_W_kernel(const float* __restrict__ attn_W,
                                 unsigned short* __restrict__ Wb) {
    int idx = (blockIdx.x * 256 + threadIdx.x) * 8;
    int h = idx >> 9;
    int k = idx & 511;
    const float* p = attn_W + (size_t)h * 1024 + k;
    float4 v0 = *(const float4*)p;
    float4 v1 = *(const float4*)(p + 4);
    unsigned short t[8] = {f2bf(v0.x), f2bf(v0.y), f2bf(v0.z), f2bf(v0.w),
                           f2bf(v1.x), f2bf(v1.y), f2bf(v1.z), f2bf(v1.w)};
    *(uint4*)(Wb + idx) = *(uint4*)t;
}

// ---------------------------------------------------------------------------
// K0b: snT[b][n][k] = bf16(sn[b][k][n]) -- LDS transpose, coalesced both sides
// block tile: 64 k x 128 n. LDS u32 [32 kpair][132] (k,k+1 packed per u32).
// ---------------------------------------------------------------------------
__global__ void transpose_sn_kernel(const float* __restrict__ sn,
                                    unsigned short* __restrict__ snT) {
    __shared__ unsigned ldsb[32 * 132];
    int bid = blockIdx.x;                 // 128 b * 8 kt * 8 nt
    int b = bid >> 6;
    int kt = (bid >> 3) & 7;
    int nt = bid & 7;
    int k0 = kt << 6, n0 = nt << 7;
    int t = threadIdx.x;

    // phase 1: coalesced fp32 reads (512B per row-group), pack k-pairs, LDS
    int kp_l = t >> 5;                    // 0..7
    int n4 = (t & 31) * 4;
#pragma unroll
    for (int j = 0; j < 4; ++j) {
        int kp = j * 8 + kp_l;            // 0..31
        const float* p0 = sn + ((size_t)(b * Hd + k0 + 2 * kp)) * Nn + n0 + n4;
        float4 f0 = *(const float4*)p0;
        float4 f1 = *(const float4*)(p0 + Nn);
        unsigned u[4];
        u[0] = (unsigned)f2bf(f0.x) | ((unsigned)f2bf(f1.x) << 16);
        u[1] = (unsigned)f2bf(f0.y) | ((unsigned)f2bf(f1.y) << 16);
        u[2] = (unsigned)f2bf(f0.z) | ((unsigned)f2bf(f1.z) << 16);
        u[3] = (unsigned)f2bf(f0.w) | ((unsigned)f2bf(f1.w) << 16);
        *(uint4*)&ldsb[kp * 132 + n4] = *(uint4*)u;
    }
    __syncthreads();

    // phase 2: gather k-contiguous 64B per (n, chunk), coalesced 16B stores
    int c = t & 7;                        // chunk: k-offset c*8 .. c*8+7
#pragma unroll
    for (int it = 0; it < 4; ++it) {
        int n = (t >> 3) + it * 32;
        unsigned u[4];
#pragma unroll
        for (int i = 0; i < 4; ++i) u[i] = ldsb[(c * 4 + i) * 132 + n];
        unsigned short* dst = snT + ((size_t)(b * Nn) + n0 + n) * Hd + k0 + c * 8;
        *(uint4*)dst = *(uint4*)u;
    }
}

// ---------------------------------------------------------------------------
// K1: mc_term[b,h] = sum_k attn_W[h, 512+k] * mc_hidden[b,k]   (fp32 exact)
// ---------------------------------------------------------------------------
__global__ void mc_term_kernel(const float* __restrict__ mc,
                               const float* __restrict__ attn_W,
                               float* __restrict__ mc_term) {
    int wg = (blockIdx.x * blockDim.x + threadIdx.x) >> 6;
    int lane = threadIdx.x & 63;
    int b = wg >> 9;
    int h = wg & 511;
    const float* m = mc + b * Hd + lane * 8;
    const float* w = attn_W + (size_t)h * 1024 + 512 + lane * 8;
    float4 m0 = *(const float4*)m, m1 = *(const float4*)(m + 4);
    float4 w0 = *(const float4*)w, w1 = *(const float4*)(w + 4);
    float acc = m0.x * w0.x + m0.y * w0.y + m0.z * w0.z + m0.w * w0.w +
                m1.x * w1.x + m1.y * w1.y + m1.z * w1.z + m1.w * w1.w;
    acc = wave_sum(acc);
    if (lane == 0) mc_term[b * Hd + h] = acc;
}

// ---------------------------------------------------------------------------
// K2: scores[b,n] -- m97-style LDS-staged MFMA GEMM.
// WG = (b, 64-n tile); wave w owns m-rows [w*128, w*128+128). BK=64, K=512.
// global_load_lds width 16 with XOR chunk swizzle (conflict-free ds_read_b128).
// ---------------------------------------------------------------------------
__global__ __launch_bounds__(256, 2)
void attn_score_kernel(const unsigned short* __restrict__ snT,
                       const unsigned short* __restrict__ Wb,
                       const float* __restrict__ attn_v,
                       const float* __restrict__ mc_term,
                       float* __restrict__ scores) {
    __shared__ __align__(16) unsigned short A_lds[512 * 64];  // [m][k] 64KB
    __shared__ __align__(16) unsigned short B_lds[64 * 64];   // [n][k] 8KB
    __shared__ float av_s[512];
    __shared__ float mct_s[512];
    __shared__ float ssum[64];

    const int b = blockIdx.x >> 4;
    const int n0 = (blockIdx.x & 15) << 6;
    const int tid = threadIdx.x;
    const int lane = tid & 63;
    const int wid = tid >> 6;
    const int quad = lane >> 4;
    const int l15 = lane & 15;
    const int m0 = wid * 128;

    av_s[tid] = attn_v[tid];
    av_s[tid + 256] = attn_v[tid + 256];
    mct_s[tid] = mc_term[b * Hd + tid];
    mct_s[tid + 256] = mc_term[b * Hd + tid + 256];
    if (tid < 64) ssum[tid] = 0.f;

    f32x4 acc[8][4];
#pragma unroll
    for (int i = 0; i < 8; ++i)
#pragma unroll
        for (int j = 0; j < 4; ++j) {
            f32x4 z = {0.f, 0.f, 0.f, 0.f};
            acc[i][j] = z;
        }

    const int r8 = lane >> 3;                  // row within 8-row staging group
    const int csw = ((lane & 7) ^ r8) * 16;    // swizzled chunk byte offset
    const char* Wg = (const char*)Wb;          // row stride 1024 B
    const char* Bg = (const char*)snT + ((size_t)(b * Nn + n0)) * 1024;
    const int key = l15 & 7;

    for (int k0 = 0; k0 < 512; k0 += 64) {
        // stage A: this wave's 128 m-rows, 16 instrs x 1KB
#pragma unroll
        for (int i = 0; i < 16; ++i) {
            const int row = m0 + i * 8;
            GLOAD_LDS16(Wg + (size_t)(row + r8) * 1024 + k0 * 2 + csw,
                        (char*)A_lds + row * 128);
        }
        // stage B: wave's 16 n-rows, 2 instrs
#pragma unroll
        for (int i = 0; i < 2; ++i) {
            const int row = wid * 16 + i * 8;
            GLOAD_LDS16(Bg + (size_t)(row + r8) * 1024 + k0 * 2 + csw,
                        (char*)B_lds + row * 128);
        }
        __syncthreads();
#pragma unroll
        for (int kk = 0; kk < 2; ++kk) {
            const int cb = quad + kk * 4;
            short8 bfr[4], afr[8];
#pragma unroll
            for (int nt = 0; nt < 4; ++nt) {
                const int n = nt * 16 + l15;
                bfr[nt] = *(const short8*)((const char*)B_lds + n * 128 + ((cb ^ key) * 16));
            }
#pragma unroll
            for (int mt = 0; mt < 8; ++mt) {
                const int m = m0 + mt * 16 + l15;
                afr[mt] = *(const short8*)((const char*)A_lds + m * 128 + ((cb ^ key) * 16));
            }
#pragma unroll
            for (int mt = 0; mt < 8; ++mt)
#pragma unroll
                for (int nt = 0; nt < 4; ++nt)
                    acc[mt][nt] = __builtin_amdgcn_mfma_f32_16x16x32_bf16(afr[mt], bfr[nt], acc[mt][nt], 0, 0, 0);
        }
        __syncthreads();
    }

    // epilogue: tanh + attn_v dot, reduce over h
    float s[4] = {0.f, 0.f, 0.f, 0.f};
#pragma unroll
    for (int mt = 0; mt < 8; ++mt) {
        int hb = m0 + mt * 16 + quad * 4;
#pragma unroll
        for (int r = 0; r < 4; ++r) {
            float av = av_s[hb + r];
            float mcv = mct_s[hb + r];
#pragma unroll
            for (int nt = 0; nt < 4; ++nt)
                s[nt] += av * tanh_fast(acc[mt][nt][r] + mcv);
        }
    }
#pragma unroll
    for (int nt = 0; nt < 4; ++nt) {
        float v = s[nt];
        v += __shfl_xor(v, 16);
        v += __shfl_xor(v, 32);
        if (lane < 16) atomicAdd(&ssum[nt * 16 + l15], v);
    }
    __syncthreads();
    if (tid < 64) scores[b * Nn + n0 + tid] = ssum[tid];
}

// ---------------------------------------------------------------------------
// K3: softmax over n per batch row (in-place)
// ---------------------------------------------------------------------------
__global__ void softmax_kernel(float* __restrict__ scores) {
    const int b = blockIdx.x;
    const int tid = threadIdx.x;
    const int lane = tid & 63, wid = tid >> 6;
    __shared__ float red[4];
    float v[4];
#pragma unroll
    for (int i = 0; i < 4; ++i) v[i] = scores[b * Nn + tid + i * 256];
    float m = fmaxf(fmaxf(v[0], v[1]), fmaxf(v[2], v[3]));
#pragma unroll
    for (int off = 32; off >= 1; off >>= 1) m = fmaxf(m, __shfl_xor(m, off));
    if (lane == 0) red[wid] = m;
    __syncthreads();
    m = fmaxf(fmaxf(red[0], red[1]), fmaxf(red[2], red[3]));
    __syncthreads();
    float s = 0.f;
#pragma unroll
    for (int i = 0; i < 4; ++i) {
        v[i] = __expf(v[i] - m);
        s += v[i];
    }
    s = wave_sum(s);
    if (lane == 0) red[wid] = s;
    __syncthreads();
    s = red[0] + red[1] + red[2] + red[3];
    float inv = __builtin_amdgcn_rcpf(s);
#pragma unroll
    for (int i = 0; i < 4; ++i) scores[b * Nn + tid + i * 256] = v[i] * inv;
}

// ---------------------------------------------------------------------------
// K4: context[b,h] += sum_n attns[b,n] * snT[b][n][h-pair]
// ---------------------------------------------------------------------------
__global__ void context_kernel(const unsigned short* __restrict__ snT,
                               const float* __restrict__ attns,
                               float* __restrict__ context) {
    int b = blockIdx.x >> 3;
    int nc = (blockIdx.x & 7) << 7;
    int t = threadIdx.x;
    __shared__ float a_s[128];
    if (t < 128) a_s[t] = attns[b * Nn + nc + t];
    __syncthreads();
    const unsigned short* base = snT + ((size_t)(b * Nn) + nc) * Hd + t * 2;
    float acc0 = 0.f, acc1 = 0.f;
#pragma unroll 4
    for (int i = 0; i < 128; ++i) {
        unsigned d = *(const unsigned*)(base + (size_t)i * Hd);
        float a = a_s[i];
        acc0 += a * bf2f(d & 0xffffu);
        acc1 += a * bf2f(d >> 16);
    }
    atomicAdd(&context[b * Hd + 2 * t], acc0);
    atomicAdd(&context[b * Hd + 2 * t + 1], acc1);
}

// ---------------------------------------------------------------------------
// K5: out1[b,h] = relu( dot([mc|context], fc1_W[h,:]) + fc1_b[h] )   (fp32)
// ---------------------------------------------------------------------------
__global__ void fc1_kernel(const float* __restrict__ mc,
                           const float* __restrict__ ctx,
                           const float* __restrict__ fc1_W,
                           const float* __restrict__ fc1_b,
                           float* __restrict__ out1) {
    int wg = (blockIdx.x * blockDim.x + threadIdx.x) >> 6;
    int lane = threadIdx.x & 63;
    int b = wg >> 9, h = wg & 511;
    const float* wr = fc1_W + (size_t)h * 1024;
    float acc = 0.f;
    {
        float4 w0 = *(const float4*)(wr + lane * 8);
        float4 w1 = *(const float4*)(wr + lane * 8 + 4);
        float4 x0 = *(const float4*)(mc + b * Hd + lane * 8);
        float4 x1 = *(const float4*)(mc + b * Hd + lane * 8 + 4);
        acc += w0.x * x0.x + w0.y * x0.y + w0.z * x0.z + w0.w * x0.w;
        acc += w1.x * x1.x + w1.y * x1.y + w1.z * x1.z + w1.w * x1.w;
    }
    {
        float4 w0 = *(const float4*)(wr + 512 + lane * 8);
        float4 w1 = *(const float4*)(wr + 512 + lane * 8 + 4);
        float4 x0 = *(const float4*)(ctx + b * Hd + lane * 8);
        float4 x1 = *(const float4*)(ctx + b * Hd + lane * 8 + 4);
        acc += w0.x * x0.x + w0.y * x0.y + w0.z * x0.z + w0.w * x0.w;
        acc += w1.x * x1.x + w1.y * x1.y + w1.z * x1.z + w1.w * x1.w;
    }
    acc = wave_sum(acc);
    if (lane == 0) out1[b * Hd + h] = fmaxf(acc + fc1_b[h], 0.f);
}

// ---------------------------------------------------------------------------
// K6: out2[b,h] = relu( dot(out1, fc2_W[h,:]) + fc2_b[h] )   (fp32)
// ---------------------------------------------------------------------------
__global__ void fc2_kernel(const float* __restrict__ out1,
                           const float* __restrict__ fc2_W,
                           const float* __restrict__ fc2_b,
                           float* __restrict__ out2) {
    int wg = (blockIdx.x * blockDim.x + threadIdx.x) >> 6;
    int lane = threadIdx.x & 63;
    int b = wg >> 9, h = wg & 511;
    const float* wr = fc2_W + (size_t)h * 512 + lane * 8;
    float4 w0 = *(const float4*)wr;
    float4 w1 = *(const float4*)(wr + 4);
    float4 x0 = *(const float4*)(out1 + b * Hd + lane * 8);
    float4 x1 = *(const float4*)(out1 + b * Hd + lane * 8 + 4);
    float acc = w0.x * x0.x + w0.y * x0.y + w0.z * x0.z + w0.w * x0.w +
                w1.x * x1.x + w1.y * x1.y + w1.z * x1.z + w1.w * x1.w;
    acc = wave_sum(acc);
    if (lane == 0) out2[b * Hd + h] = fmaxf(acc + fc2_b[h], 0.f);
}

// ---------------------------------------------------------------------------
// K7: probs[b,n] = sum_h ptr_v[h] * tanh( snT[b][n][h] + out2[b,h] )
// ---------------------------------------------------------------------------
__global__ void final_kernel(const unsigned short* __restrict__ snT,
                             const float* __restrict__ ptr_v,
                             const float* __restrict__ out2,
                             float* __restrict__ probs) {
    int b = blockIdx.x >> 4;
    int n0 = (blockIdx.x & 15) << 6;
    int t = threadIdx.x;
    int n = n0 + (t >> 2), p = t & 3;
    __shared__ float pv_s[512], o2_s[512];
    pv_s[t] = ptr_v[t];
    pv_s[t + 256] = ptr_v[t + 256];
    o2_s[t] = out2[b * Hd + t];
    o2_s[t + 256] = out2[b * Hd + t + 256];
    __syncthreads();
    const unsigned short* row = snT + ((size_t)(b * Nn) + n) * Hd + p * 8;
    float a = 0.f;
#pragma unroll 4
    for (int j = 0; j < 16; ++j) {
        uint4 d = *(const uint4*)(row + j * 32);
        int hb = p * 8 + j * 32;
        const unsigned* u = (const unsigned*)&d;
#pragma unroll
        for (int q = 0; q < 4; ++q) {
            int h = hb + q * 2;
            float x0 = bf2f(u[q] & 0xffffu);
            float x1 = bf2f(u[q] >> 16);
            a += pv_s[h] * tanh_fast(x0 + o2_s[h]);
            a += pv_s[h + 1] * tanh_fast(x1 + o2_s[h + 1]);
        }
    }
    a += __shfl_xor(a, 1);
    a += __shfl_xor(a, 2);
    if (p == 0) probs[b * Nn + n] = a;
}

// ---------------------------------------------------------------------------
extern "C" void kernel_launch(void* const* d_in, const int* in_sizes, int n_in,
                              void* d_out, int out_size, void* d_ws, size_t ws_size,
                              hipStream_t stream) {
    const float* mc  = (const float*)d_in[0];
    const float* sn  = (const float*)d_in[1];
    const float* aW  = (const float*)d_in[2];
    const float* av  = (const float*)d_in[3];
    const float* pv  = (const float*)d_in[4];
    const float* f1W = (const float*)d_in[5];
    const float* f1b = (const float*)d_in[6];
    const float* f2W = (const float*)d_in[7];
    const float* f2b = (const float*)d_in[8];

    unsigned short* snT = (unsigned short*)d_ws;            // 128 MB
    unsigned short* Wb  = snT + (size_t)Bn * Nn * Hd;       // 512 KB
    float* fws     = (float*)(Wb + 512 * 512);
    float* mc_term = fws;
    float* scores  = mc_term + Bn * Hd;
    float* context = scores + Bn * Nn;
    float* out1    = context + Bn * Hd;
    float* out2    = out1 + Bn * Hd;
    float* probs   = (float*)d_out;

    hipMemsetAsync(context, 0, Bn * Hd * sizeof(float), stream);
    convert_W_kernel<<<dim3(128), dim3(256), 0, stream>>>(aW, Wb);
    transpose_sn_kernel<<<dim3(8192), dim3(256), 0, stream>>>(sn, snT);
    mc_term_kernel<<<dim3(16384), dim3(256), 0, stream>>>(mc, aW, mc_term);
    attn_score_kernel<<<dim3(2048), dim3(256), 0, stream>>>(snT, Wb, av, mc_term, scores);
    softmax_kernel<<<dim3(128), dim3(256), 0, stream>>>(scores);
    context_kernel<<<dim3(1024), dim3(256), 0, stream>>>(snT, scores, context);
    fc1_kernel<<<dim3(16384), dim3(256), 0, stream>>>(mc, context, f1W, f1b, out1);
    fc2_kernel<<<dim3(16384), dim3(256), 0, stream>>>(out1, f2W, f2b, out2);
    final_kernel<<<dim3(2048), dim3(256), 0, stream>>>(snT, pv, out2, probs);
}

// Round 2
// 552.739 us; speedup vs baseline: 1.0235x; 1.0235x over previous
//
#include <hip/hip_runtime.h>
#include <hip/hip_bf16.h>

#define Bn 128
#define Hd 512
#define Nn 1024

typedef __attribute__((ext_vector_type(8))) short short8;
typedef __attribute__((ext_vector_type(4))) float f32x4;

#define GLOAD_LDS16(gptr, lptr)                                                     \
    __builtin_amdgcn_global_load_lds(                                               \
        (const __attribute__((address_space(1))) void*)(gptr),                      \
        (__attribute__((address_space(3))) void*)(lptr), 16, 0, 0)

__device__ __forceinline__ float bf2f(unsigned u) {
    unsigned v = u << 16;
    float f;
    __builtin_memcpy(&f, &v, 4);
    return f;
}

__device__ __forceinline__ unsigned short f2bf(float f) {
    unsigned x;
    __builtin_memcpy(&x, &f, 4);
    unsigned r = x + 0x7fffu + ((x >> 16) & 1u);
    return (unsigned short)(r >> 16);
}

// packed RNE f32x2 -> bf16x2 (compiler emits v_cvt_pk_bf16_f32)
__device__ __forceinline__ unsigned pack_bf2(float a, float b) {
    __hip_bfloat162 h = __float22bfloat162_rn(float2{a, b});
    unsigned u;
    __builtin_memcpy(&u, &h, 4);
    return u;
}

__device__ __forceinline__ float wave_sum(float v) {
    v += __shfl_xor(v, 32);
    v += __shfl_xor(v, 16);
    v += __shfl_xor(v, 8);
    v += __shfl_xor(v, 4);
    v += __shfl_xor(v, 2);
    v += __shfl_xor(v, 1);
    return v;
}

__device__ __forceinline__ float tanh_fast(float x) {
    float e = __expf(2.0f * x);
    return 1.0f - 2.0f * __builtin_amdgcn_rcpf(e + 1.0f);
}

// ---------------------------------------------------------------------------
// K0a: Wb[h][k] = bf16(attn_W[h][k]), k in [0,512)
// ---------------------------------------------------------------------------
__global__ void convert_W_kernel(const float* __restrict__ attn_W,
                                 unsigned short* __restrict__ Wb) {
    int idx = (blockIdx.x * 256 + threadIdx.x) * 8;
    int h = idx >> 9;
    int k = idx & 511;
    const float* p = attn_W + (size_t)h * 1024 + k;
    float4 v0 = *(const float4*)p;
    float4 v1 = *(const float4*)(p + 4);
    unsigned u[4] = {pack_bf2(v0.x, v0.y), pack_bf2(v0.z, v0.w),
                     pack_bf2(v1.x, v1.y), pack_bf2(v1.z, v1.w)};
    *(uint4*)(Wb + idx) = *(uint4*)u;
}

// ---------------------------------------------------------------------------
// K0b: snT[b][n][k] = bf16(sn[b][k][n]) -- LDS transpose, coalesced both sides
// block tile: 64 k x 128 n. LDS u32 [32 kpair][132] (k,k+1 packed per u32).
// ---------------------------------------------------------------------------
__global__ void transpose_sn_kernel(const float* __restrict__ sn,
                                    unsigned short* __restrict__ snT) {
    __shared__ unsigned ldsb[32 * 132];
    int bid = blockIdx.x;                 // 128 b * 8 kt * 8 nt
    int b = bid >> 6;
    int kt = (bid >> 3) & 7;
    int nt = bid & 7;
    int k0 = kt << 6, n0 = nt << 7;
    int t = threadIdx.x;

    // phase 1: coalesced fp32 reads (512B per row-group), pack k-pairs, LDS
    int kp_l = t >> 5;                    // 0..7
    int n4 = (t & 31) * 4;
#pragma unroll
    for (int j = 0; j < 4; ++j) {
        int kp = j * 8 + kp_l;            // 0..31
        const float* p0 = sn + ((size_t)(b * Hd + k0 + 2 * kp)) * Nn + n0 + n4;
        float4 f0 = *(const float4*)p0;
        float4 f1 = *(const float4*)(p0 + Nn);
        unsigned u[4];
        u[0] = pack_bf2(f0.x, f1.x);
        u[1] = pack_bf2(f0.y, f1.y);
        u[2] = pack_bf2(f0.z, f1.z);
        u[3] = pack_bf2(f0.w, f1.w);
        *(uint4*)&ldsb[kp * 132 + n4] = *(uint4*)u;
    }
    __syncthreads();

    // phase 2: gather k-contiguous 64B per (n, chunk), coalesced 16B stores
    int c = t & 7;                        // chunk: k-offset c*8 .. c*8+7
#pragma unroll
    for (int it = 0; it < 4; ++it) {
        int n = (t >> 3) + it * 32;
        unsigned u[4];
#pragma unroll
        for (int i = 0; i < 4; ++i) u[i] = ldsb[(c * 4 + i) * 132 + n];
        unsigned short* dst = snT + ((size_t)(b * Nn) + n0 + n) * Hd + k0 + c * 8;
        *(uint4*)dst = *(uint4*)u;
    }
}

// ---------------------------------------------------------------------------
// K1: mc_term[b,h] = sum_k attn_W[h, 512+k] * mc_hidden[b,k]   (fp32 exact)
// ---------------------------------------------------------------------------
__global__ void mc_term_kernel(const float* __restrict__ mc,
                               const float* __restrict__ attn_W,
                               float* __restrict__ mc_term) {
    int wg = (blockIdx.x * blockDim.x + threadIdx.x) >> 6;
    int lane = threadIdx.x & 63;
    int b = wg >> 9;
    int h = wg & 511;
    const float* m = mc + b * Hd + lane * 8;
    const float* w = attn_W + (size_t)h * 1024 + 512 + lane * 8;
    float4 m0 = *(const float4*)m, m1 = *(const float4*)(m + 4);
    float4 w0 = *(const float4*)w, w1 = *(const float4*)(w + 4);
    float acc = m0.x * w0.x + m0.y * w0.y + m0.z * w0.z + m0.w * w0.w +
                m1.x * w1.x + m1.y * w1.y + m1.z * w1.z + m1.w * w1.w;
    acc = wave_sum(acc);
    if (lane == 0) mc_term[b * Hd + h] = acc;
}

// ---------------------------------------------------------------------------
// K2: scores[b,n] partial -- BM=256 x BN=128 x BK=64 MFMA GEMM.
// grid = b(128) x mh(2) x ntile(8). 4 waves; wave w owns m [w*64,w*64+64),
// all 128 n. R = MFMA:stage = 64:12 (was 64:18 at BM512/BN64).
// Epilogue: partial sum_h av*tanh(acc+mct) -> atomicAdd into scores (zeroed).
// ---------------------------------------------------------------------------
__global__ __launch_bounds__(256, 2)
void attn_score_kernel(const unsigned short* __restrict__ snT,
                       const unsigned short* __restrict__ Wb,
                       const float* __restrict__ attn_v,
                       const float* __restrict__ mc_term,
                       float* __restrict__ scores) {
    __shared__ __align__(16) unsigned short A_lds[256 * 64];  // [m][k] 32KB
    __shared__ __align__(16) unsigned short B_lds[128 * 64];  // [n][k] 16KB
    __shared__ float av_s[256];
    __shared__ float mct_s[256];
    __shared__ float ssum[128];

    const int bid = blockIdx.x;
    const int b = bid >> 4;
    const int mh = (bid >> 3) & 1;        // m-half: rows [mh*256, mh*256+256)
    const int n0 = (bid & 7) << 7;        // 128-wide n tile
    const int tid = threadIdx.x;
    const int lane = tid & 63;
    const int wid = tid >> 6;
    const int quad = lane >> 4;
    const int l15 = lane & 15;

    av_s[tid] = attn_v[mh * 256 + tid];
    mct_s[tid] = mc_term[b * Hd + mh * 256 + tid];
    if (tid < 128) ssum[tid] = 0.f;

    f32x4 acc[4][8];
#pragma unroll
    for (int i = 0; i < 4; ++i)
#pragma unroll
        for (int j = 0; j < 8; ++j) {
            f32x4 z = {0.f, 0.f, 0.f, 0.f};
            acc[i][j] = z;
        }

    const int r8 = lane >> 3;                  // row within 8-row staging group
    const int csw = ((lane & 7) ^ r8) * 16;    // swizzled chunk byte offset
    const char* Wg = (const char*)Wb + (size_t)(mh * 256) * 1024;  // row stride 1024 B
    const char* Bg = (const char*)snT + ((size_t)(b * Nn + n0)) * 1024;
    const int key = l15 & 7;

    for (int k0 = 0; k0 < 512; k0 += 64) {
        // stage A: wave's 64 m-rows, 8 instrs x 1KB
#pragma unroll
        for (int i = 0; i < 8; ++i) {
            const int row = wid * 64 + i * 8;
            GLOAD_LDS16(Wg + (size_t)(row + r8) * 1024 + k0 * 2 + csw,
                        (char*)A_lds + row * 128);
        }
        // stage B: wave's 32 n-rows, 4 instrs
#pragma unroll
        for (int i = 0; i < 4; ++i) {
            const int row = wid * 32 + i * 8;
            GLOAD_LDS16(Bg + (size_t)(row + r8) * 1024 + k0 * 2 + csw,
                        (char*)B_lds + row * 128);
        }
        __syncthreads();
#pragma unroll
        for (int kk = 0; kk < 2; ++kk) {
            const int cb = quad + kk * 4;
            short8 bfr[8], afr[4];
#pragma unroll
            for (int nt = 0; nt < 8; ++nt) {
                const int n = nt * 16 + l15;
                bfr[nt] = *(const short8*)((const char*)B_lds + n * 128 + ((cb ^ key) * 16));
            }
#pragma unroll
            for (int mt = 0; mt < 4; ++mt) {
                const int m = wid * 64 + mt * 16 + l15;
                afr[mt] = *(const short8*)((const char*)A_lds + m * 128 + ((cb ^ key) * 16));
            }
#pragma unroll
            for (int mt = 0; mt < 4; ++mt)
#pragma unroll
                for (int nt = 0; nt < 8; ++nt)
                    acc[mt][nt] = __builtin_amdgcn_mfma_f32_16x16x32_bf16(afr[mt], bfr[nt], acc[mt][nt], 0, 0, 0);
        }
        __syncthreads();
    }

    // epilogue: tanh + attn_v dot over this block's 256 h, reduce, atomic out
    float s[8] = {0.f, 0.f, 0.f, 0.f, 0.f, 0.f, 0.f, 0.f};
#pragma unroll
    for (int mt = 0; mt < 4; ++mt) {
        int hb = wid * 64 + mt * 16 + quad * 4;
#pragma unroll
        for (int r = 0; r < 4; ++r) {
            float av = av_s[hb + r];
            float mcv = mct_s[hb + r];
#pragma unroll
            for (int nt = 0; nt < 8; ++nt)
                s[nt] += av * tanh_fast(acc[mt][nt][r] + mcv);
        }
    }
#pragma unroll
    for (int nt = 0; nt < 8; ++nt) {
        float v = s[nt];
        v += __shfl_xor(v, 16);
        v += __shfl_xor(v, 32);
        if (lane < 16) atomicAdd(&ssum[nt * 16 + l15], v);
    }
    __syncthreads();
    if (tid < 128) atomicAdd(&scores[b * Nn + n0 + tid], ssum[tid]);
}

// ---------------------------------------------------------------------------
// K3+K4 fused: softmax (recomputed per n-chunk block, trivial) + context
// context[b,h] += sum_n attns[b,n] * snT[b][n][h-pair]
// ---------------------------------------------------------------------------
__global__ void softmax_context_kernel(const unsigned short* __restrict__ snT,
                                       const float* __restrict__ scores,
                                       float* __restrict__ context) {
    int b = blockIdx.x >> 3;
    int nc = (blockIdx.x & 7) << 7;
    int t = threadIdx.x;
    int lane = t & 63, wid = t >> 6;
    __shared__ float red[4];
    __shared__ float a_s[128];

    // full-row softmax stats (4 KB read, redundant across the 8 chunk-blocks)
    float v[4];
#pragma unroll
    for (int i = 0; i < 4; ++i) v[i] = scores[b * Nn + t + i * 256];
    float m = fmaxf(fmaxf(v[0], v[1]), fmaxf(v[2], v[3]));
#pragma unroll
    for (int off = 32; off >= 1; off >>= 1) m = fmaxf(m, __shfl_xor(m, off));
    if (lane == 0) red[wid] = m;
    __syncthreads();
    m = fmaxf(fmaxf(red[0], red[1]), fmaxf(red[2], red[3]));
    __syncthreads();
    float s = 0.f;
#pragma unroll
    for (int i = 0; i < 4; ++i) s += __expf(v[i] - m);
    s = wave_sum(s);
    if (lane == 0) red[wid] = s;
    __syncthreads();
    s = red[0] + red[1] + red[2] + red[3];
    float inv = __builtin_amdgcn_rcpf(s);
    if (t < 128) a_s[t] = __expf(scores[b * Nn + nc + t] - m) * inv;
    __syncthreads();

    // context partial over this 128-n chunk
    const unsigned short* base = snT + ((size_t)(b * Nn) + nc) * Hd + t * 2;
    float acc0 = 0.f, acc1 = 0.f;
#pragma unroll 4
    for (int i = 0; i < 128; ++i) {
        unsigned d = *(const unsigned*)(base + (size_t)i * Hd);
        float a = a_s[i];
        acc0 += a * bf2f(d & 0xffffu);
        acc1 += a * bf2f(d >> 16);
    }
    atomicAdd(&context[b * Hd + 2 * t], acc0);
    atomicAdd(&context[b * Hd + 2 * t + 1], acc1);
}

// ---------------------------------------------------------------------------
// K5: out1[b,h] = relu( dot([mc|context], fc1_W[h,:]) + fc1_b[h] )   (fp32)
// ---------------------------------------------------------------------------
__global__ void fc1_kernel(const float* __restrict__ mc,
                           const float* __restrict__ ctx,
                           const float* __restrict__ fc1_W,
                           const float* __restrict__ fc1_b,
                           float* __restrict__ out1) {
    int wg = (blockIdx.x * blockDim.x + threadIdx.x) >> 6;
    int lane = threadIdx.x & 63;
    int b = wg >> 9, h = wg & 511;
    const float* wr = fc1_W + (size_t)h * 1024;
    float acc = 0.f;
    {
        float4 w0 = *(const float4*)(wr + lane * 8);
        float4 w1 = *(const float4*)(wr + lane * 8 + 4);
        float4 x0 = *(const float4*)(mc + b * Hd + lane * 8);
        float4 x1 = *(const float4*)(mc + b * Hd + lane * 8 + 4);
        acc += w0.x * x0.x + w0.y * x0.y + w0.z * x0.z + w0.w * x0.w;
        acc += w1.x * x1.x + w1.y * x1.y + w1.z * x1.z + w1.w * x1.w;
    }
    {
        float4 w0 = *(const float4*)(wr + 512 + lane * 8);
        float4 w1 = *(const float4*)(wr + 512 + lane * 8 + 4);
        float4 x0 = *(const float4*)(ctx + b * Hd + lane * 8);
        float4 x1 = *(const float4*)(ctx + b * Hd + lane * 8 + 4);
        acc += w0.x * x0.x + w0.y * x0.y + w0.z * x0.z + w0.w * x0.w;
        acc += w1.x * x1.x + w1.y * x1.y + w1.z * x1.z + w1.w * x1.w;
    }
    acc = wave_sum(acc);
    if (lane == 0) out1[b * Hd + h] = fmaxf(acc + fc1_b[h], 0.f);
}

// ---------------------------------------------------------------------------
// K6: out2[b,h] = relu( dot(out1, fc2_W[h,:]) + fc2_b[h] )   (fp32)
// ---------------------------------------------------------------------------
__global__ void fc2_kernel(const float* __restrict__ out1,
                           const float* __restrict__ fc2_W,
                           const float* __restrict__ fc2_b,
                           float* __restrict__ out2) {
    int wg = (blockIdx.x * blockDim.x + threadIdx.x) >> 6;
    int lane = threadIdx.x & 63;
    int b = wg >> 9, h = wg & 511;
    const float* wr = fc2_W + (size_t)h * 512 + lane * 8;
    float4 w0 = *(const float4*)wr;
    float4 w1 = *(const float4*)(wr + 4);
    float4 x0 = *(const float4*)(out1 + b * Hd + lane * 8);
    float4 x1 = *(const float4*)(out1 + b * Hd + lane * 8 + 4);
    float acc = w0.x * x0.x + w0.y * x0.y + w0.z * x0.z + w0.w * x0.w +
                w1.x * x1.x + w1.y * x1.y + w1.z * x1.z + w1.w * x1.w;
    acc = wave_sum(acc);
    if (lane == 0) out2[b * Hd + h] = fmaxf(acc + fc2_b[h], 0.f);
}

// ---------------------------------------------------------------------------
// K7: probs[b,n] = sum_h ptr_v[h] * tanh( snT[b][n][h] + out2[b,h] )
// ---------------------------------------------------------------------------
__global__ void final_kernel(const unsigned short* __restrict__ snT,
                             const float* __restrict__ ptr_v,
                             const float* __restrict__ out2,
                             float* __restrict__ probs) {
    int b = blockIdx.x >> 4;
    int n0 = (blockIdx.x & 15) << 6;
    int t = threadIdx.x;
    int n = n0 + (t >> 2), p = t & 3;
    __shared__ float pv_s[512], o2_s[512];
    pv_s[t] = ptr_v[t];
    pv_s[t + 256] = ptr_v[t + 256];
    o2_s[t] = out2[b * Hd + t];
    o2_s[t + 256] = out2[b * Hd + t + 256];
    __syncthreads();
    const unsigned short* row = snT + ((size_t)(b * Nn) + n) * Hd + p * 8;
    float a = 0.f;
#pragma unroll 4
    for (int j = 0; j < 16; ++j) {
        uint4 d = *(const uint4*)(row + j * 32);
        int hb = p * 8 + j * 32;
        const unsigned* u = (const unsigned*)&d;
#pragma unroll
        for (int q = 0; q < 4; ++q) {
            int h = hb + q * 2;
            float x0 = bf2f(u[q] & 0xffffu);
            float x1 = bf2f(u[q] >> 16);
            a += pv_s[h] * tanh_fast(x0 + o2_s[h]);
            a += pv_s[h + 1] * tanh_fast(x1 + o2_s[h + 1]);
        }
    }
    a += __shfl_xor(a, 1);
    a += __shfl_xor(a, 2);
    if (p == 0) probs[b * Nn + n] = a;
}

// ---------------------------------------------------------------------------
extern "C" void kernel_launch(void* const* d_in, const int* in_sizes, int n_in,
                              void* d_out, int out_size, void* d_ws, size_t ws_size,
                              hipStream_t stream) {
    const float* mc  = (const float*)d_in[0];
    const float* sn  = (const float*)d_in[1];
    const float* aW  = (const float*)d_in[2];
    const float* av  = (const float*)d_in[3];
    const float* pv  = (const float*)d_in[4];
    const float* f1W = (const float*)d_in[5];
    const float* f1b = (const float*)d_in[6];
    const float* f2W = (const float*)d_in[7];
    const float* f2b = (const float*)d_in[8];

    unsigned short* snT = (unsigned short*)d_ws;            // 128 MB
    unsigned short* Wb  = snT + (size_t)Bn * Nn * Hd;       // 512 KB
    float* fws     = (float*)(Wb + 512 * 512);
    float* mc_term = fws;
    float* scores  = mc_term + Bn * Hd;                     // zeroed (atomics)
    float* context = scores + Bn * Nn;                      // zeroed (atomics)
    float* out1    = context + Bn * Hd;
    float* out2    = out1 + Bn * Hd;
    float* probs   = (float*)d_out;

    // one memset covers scores (512 KB) + context (256 KB), contiguous
    hipMemsetAsync(scores, 0, (Bn * Nn + Bn * Hd) * sizeof(float), stream);
    convert_W_kernel<<<dim3(128), dim3(256), 0, stream>>>(aW, Wb);
    transpose_sn_kernel<<<dim3(8192), dim3(256), 0, stream>>>(sn, snT);
    mc_term_kernel<<<dim3(16384), dim3(256), 0, stream>>>(mc, aW, mc_term);
    attn_score_kernel<<<dim3(2048), dim3(256), 0, stream>>>(snT, Wb, av, mc_term, scores);
    softmax_context_kernel<<<dim3(1024), dim3(256), 0, stream>>>(snT, scores, context);
    fc1_kernel<<<dim3(16384), dim3(256), 0, stream>>>(mc, context, f1W, f1b, out1);
    fc2_kernel<<<dim3(16384), dim3(256), 0, stream>>>(out1, f2W, f2b, out2);
    final_kernel<<<dim3(2048), dim3(256), 0, stream>>>(snT, pv, out2, probs);
}

// Round 3
// 527.298 us; speedup vs baseline: 1.0729x; 1.0482x over previous
//
#include <hip/hip_runtime.h>
#include <hip/hip_bf16.h>

#define Bn 128
#define Hd 512
#define Nn 1024

typedef __attribute__((ext_vector_type(8))) short short8;
typedef __attribute__((ext_vector_type(4))) float f32x4;

#define GLOAD_LDS16(gptr, lptr)                                                     \
    __builtin_amdgcn_global_load_lds(                                               \
        (const __attribute__((address_space(1))) void*)(gptr),                      \
        (__attribute__((address_space(3))) void*)(lptr), 16, 0, 0)

// packed RNE f32x2 -> bf16x2 (compiler emits v_cvt_pk_bf16_f32)
__device__ __forceinline__ unsigned pack_bf2(float a, float b) {
    __hip_bfloat162 h = __float22bfloat162_rn(float2{a, b});
    unsigned u;
    __builtin_memcpy(&u, &h, 4);
    return u;
}

__device__ __forceinline__ float wave_sum(float v) {
    v += __shfl_xor(v, 32);
    v += __shfl_xor(v, 16);
    v += __shfl_xor(v, 8);
    v += __shfl_xor(v, 4);
    v += __shfl_xor(v, 2);
    v += __shfl_xor(v, 1);
    return v;
}

__device__ __forceinline__ float tanh_fast(float x) {
    float e = __expf(2.0f * x);
    return 1.0f - 2.0f * __builtin_amdgcn_rcpf(e + 1.0f);
}

// ---------------------------------------------------------------------------
// K0: fused preprocessing.
//   blocks [0,128):    Wb[h][k] = bf16(attn_W[h][k]), k in [0,512)
//   blocks [128,16512): mc_term[b,h] = sum_k attn_W[h,512+k]*mc[b,k]  (fp32)
// ---------------------------------------------------------------------------
__global__ void pre_kernel(const float* __restrict__ attn_W,
                           const float* __restrict__ mc,
                           unsigned short* __restrict__ Wb,
                           float* __restrict__ mc_term) {
    if (blockIdx.x < 128) {
        int idx = (blockIdx.x * 256 + threadIdx.x) * 8;
        int h = idx >> 9;
        int k = idx & 511;
        const float* p = attn_W + (size_t)h * 1024 + k;
        float4 v0 = *(const float4*)p;
        float4 v1 = *(const float4*)(p + 4);
        unsigned u[4] = {pack_bf2(v0.x, v0.y), pack_bf2(v0.z, v0.w),
                         pack_bf2(v1.x, v1.y), pack_bf2(v1.z, v1.w)};
        *(uint4*)(Wb + idx) = *(uint4*)u;
        return;
    }
    int wg = ((blockIdx.x - 128) * 256 + threadIdx.x) >> 6;
    int lane = threadIdx.x & 63;
    int b = wg >> 9;
    int h = wg & 511;
    const float* m = mc + b * Hd + lane * 8;
    const float* w = attn_W + (size_t)h * 1024 + 512 + lane * 8;
    float4 m0 = *(const float4*)m, m1 = *(const float4*)(m + 4);
    float4 w0 = *(const float4*)w, w1 = *(const float4*)(w + 4);
    float acc = m0.x * w0.x + m0.y * w0.y + m0.z * w0.z + m0.w * w0.w +
                m1.x * w1.x + m1.y * w1.y + m1.z * w1.z + m1.w * w1.w;
    acc = wave_sum(acc);
    if (lane == 0) mc_term[b * Hd + h] = acc;
}

// ---------------------------------------------------------------------------
// K2: scores_part[mh][b][n] -- MFMA GEMM with FUSED in-kernel B transpose.
// BM=256 x BN=128 x BK=64, 4 waves; wave w owns m [w*64,w*64+64), all 128 n.
// A: bf16 Wb via global_load_lds (chunk-XOR swizzle, proven layout).
// B: sn fp32 [k][n] staged per K-step -> LDS u32 [kpair][132] (bf16 pairs);
//    fragment gather = 4 x ds_read_b32 (bank-verified 2-way = free).
// No transpose kernel, no snT, no atomics, no memset.
// ---------------------------------------------------------------------------
__global__ __launch_bounds__(256, 2)
void attn_score_kernel(const float* __restrict__ sn,
                       const unsigned short* __restrict__ Wb,
                       const float* __restrict__ attn_v,
                       const float* __restrict__ mc_term,
                       float* __restrict__ scores_part) {
    __shared__ __align__(16) unsigned short A_lds[256 * 64];  // [m][k] 32KB
    __shared__ __align__(16) unsigned B_kp[32 * 132];         // [kpair][n] 16.9KB
    __shared__ float av_s[256];
    __shared__ float mct_s[256];
    __shared__ float ssum[128];

    const int bid = blockIdx.x;
    const int b = bid >> 4;
    const int mh = (bid >> 3) & 1;        // m-half: rows [mh*256, mh*256+256)
    const int n0 = (bid & 7) << 7;        // 128-wide n tile
    const int tid = threadIdx.x;
    const int lane = tid & 63;
    const int wid = tid >> 6;
    const int quad = lane >> 4;
    const int l15 = lane & 15;

    av_s[tid] = attn_v[mh * 256 + tid];
    mct_s[tid] = mc_term[b * Hd + mh * 256 + tid];
    if (tid < 128) ssum[tid] = 0.f;

    f32x4 acc[4][8];
#pragma unroll
    for (int i = 0; i < 4; ++i)
#pragma unroll
        for (int j = 0; j < 8; ++j) {
            f32x4 z = {0.f, 0.f, 0.f, 0.f};
            acc[i][j] = z;
        }

    const int r8 = lane >> 3;                  // A-staging row within 8-group
    const int csw = ((lane & 7) ^ r8) * 16;    // A swizzled chunk byte offset
    const char* Wg = (const char*)Wb + (size_t)(mh * 256) * 1024;
    const int key = l15 & 7;

    // B staging map (transpose phase-1 style): thread -> (kpair group, 4 n)
    const int kp_l = tid >> 5;                 // 0..7
    const int n4 = (tid & 31) * 4;             // 0..124
    const float* snb = sn + (size_t)b * Hd * Nn + n0 + n4;

    for (int k0 = 0; k0 < 512; k0 += 64) {
        // stage A: wave's 64 m-rows, 8 global_load_lds x 1KB
#pragma unroll
        for (int i = 0; i < 8; ++i) {
            const int row = wid * 64 + i * 8;
            GLOAD_LDS16(Wg + (size_t)(row + r8) * 1024 + k0 * 2 + csw,
                        (char*)A_lds + row * 128);
        }
        // stage B: fp32 rows k0+2kp, k0+2kp+1 -> bf16-pair u32 [kpair][132]
#pragma unroll
        for (int j = 0; j < 4; ++j) {
            const int kp = j * 8 + kp_l;       // 0..31
            const float* p0 = snb + (size_t)(k0 + 2 * kp) * Nn;
            float4 f0 = *(const float4*)p0;
            float4 f1 = *(const float4*)(p0 + Nn);
            unsigned u[4];
            u[0] = pack_bf2(f0.x, f1.x);
            u[1] = pack_bf2(f0.y, f1.y);
            u[2] = pack_bf2(f0.z, f1.z);
            u[3] = pack_bf2(f0.w, f1.w);
            *(uint4*)&B_kp[kp * 132 + n4] = *(uint4*)u;
        }
        __syncthreads();
#pragma unroll
        for (int kk = 0; kk < 2; ++kk) {
            const int cb = quad + kk * 4;      // k-chunk: k_local = cb*8..+8
            short8 bfr[8], afr[4];
#pragma unroll
            for (int nt = 0; nt < 8; ++nt) {
                const int nl = nt * 16 + l15;
                uint4 uu;
                uu.x = B_kp[(cb * 4 + 0) * 132 + nl];
                uu.y = B_kp[(cb * 4 + 1) * 132 + nl];
                uu.z = B_kp[(cb * 4 + 2) * 132 + nl];
                uu.w = B_kp[(cb * 4 + 3) * 132 + nl];
                bfr[nt] = *(short8*)&uu;
            }
#pragma unroll
            for (int mt = 0; mt < 4; ++mt) {
                const int m = wid * 64 + mt * 16 + l15;
                afr[mt] = *(const short8*)((const char*)A_lds + m * 128 + ((cb ^ key) * 16));
            }
#pragma unroll
            for (int mt = 0; mt < 4; ++mt)
#pragma unroll
                for (int nt = 0; nt < 8; ++nt)
                    acc[mt][nt] = __builtin_amdgcn_mfma_f32_16x16x32_bf16(afr[mt], bfr[nt], acc[mt][nt], 0, 0, 0);
        }
        __syncthreads();
    }

    // epilogue: tanh + attn_v dot over this block's 256 h, reduce, store part
    float s[8] = {0.f, 0.f, 0.f, 0.f, 0.f, 0.f, 0.f, 0.f};
#pragma unroll
    for (int mt = 0; mt < 4; ++mt) {
        int hb = wid * 64 + mt * 16 + quad * 4;
#pragma unroll
        for (int r = 0; r < 4; ++r) {
            float av = av_s[hb + r];
            float mcv = mct_s[hb + r];
#pragma unroll
            for (int nt = 0; nt < 8; ++nt)
                s[nt] += av * tanh_fast(acc[mt][nt][r] + mcv);
        }
    }
#pragma unroll
    for (int nt = 0; nt < 8; ++nt) {
        float v = s[nt];
        v += __shfl_xor(v, 16);
        v += __shfl_xor(v, 32);
        if (lane < 16) atomicAdd(&ssum[nt * 16 + l15], v);
    }
    __syncthreads();
    if (tid < 128)
        scores_part[((size_t)mh * Bn + b) * Nn + n0 + tid] = ssum[tid];
}

// ---------------------------------------------------------------------------
// K3: softmax over n per batch row; input = sum of the two mh partials
// ---------------------------------------------------------------------------
__global__ void softmax_kernel(const float* __restrict__ scores_part,
                               float* __restrict__ attns) {
    const int b = blockIdx.x;
    const int tid = threadIdx.x;
    const int lane = tid & 63, wid = tid >> 6;
    __shared__ float red[4];
    const float* s0 = scores_part + (size_t)b * Nn;
    const float* s1 = scores_part + ((size_t)Bn + b) * Nn;
    float v[4];
#pragma unroll
    for (int i = 0; i < 4; ++i) {
        int idx = tid + i * 256;
        v[i] = s0[idx] + s1[idx];
    }
    float m = fmaxf(fmaxf(v[0], v[1]), fmaxf(v[2], v[3]));
#pragma unroll
    for (int off = 32; off >= 1; off >>= 1) m = fmaxf(m, __shfl_xor(m, off));
    if (lane == 0) red[wid] = m;
    __syncthreads();
    m = fmaxf(fmaxf(red[0], red[1]), fmaxf(red[2], red[3]));
    __syncthreads();
    float s = 0.f;
#pragma unroll
    for (int i = 0; i < 4; ++i) {
        v[i] = __expf(v[i] - m);
        s += v[i];
    }
    s = wave_sum(s);
    if (lane == 0) red[wid] = s;
    __syncthreads();
    s = red[0] + red[1] + red[2] + red[3];
    float inv = __builtin_amdgcn_rcpf(s);
#pragma unroll
    for (int i = 0; i < 4; ++i) attns[b * Nn + tid + i * 256] = v[i] * inv;
}

// ---------------------------------------------------------------------------
// K4: context[b,h] = sum_n attns[b,n] * sn[b][h][n]   (fp32, direct layout)
// block = (b, 64 h). thread: h = h0 + t>>2, n-phase q = t&3. No atomics.
// ---------------------------------------------------------------------------
__global__ void context_kernel(const float* __restrict__ sn,
                               const float* __restrict__ attns,
                               float* __restrict__ context) {
    int b = blockIdx.x >> 3;
    int h0 = (blockIdx.x & 7) << 6;
    int t = threadIdx.x;
    __shared__ float a_s[1024];
    *(float4*)&a_s[t * 4] = *(const float4*)&attns[b * Nn + t * 4];
    __syncthreads();
    int h = h0 + (t >> 2), q = t & 3;
    const float* row = sn + ((size_t)b * Hd + h) * Nn;
    float acc = 0.f;
#pragma unroll 8
    for (int j = 0; j < 64; ++j) {
        int n = q * 4 + j * 16;
        float4 f = *(const float4*)&row[n];
        float4 a = *(const float4*)&a_s[n];
        acc += f.x * a.x + f.y * a.y + f.z * a.z + f.w * a.w;
    }
    acc += __shfl_xor(acc, 1);
    acc += __shfl_xor(acc, 2);
    if (q == 0) context[b * Hd + h] = acc;
}

// ---------------------------------------------------------------------------
// K5: out1[b,h] = relu( dot([mc|context], fc1_W[h,:]) + fc1_b[h] )   (fp32)
// ---------------------------------------------------------------------------
__global__ void fc1_kernel(const float* __restrict__ mc,
                           const float* __restrict__ ctx,
                           const float* __restrict__ fc1_W,
                           const float* __restrict__ fc1_b,
                           float* __restrict__ out1) {
    int wg = (blockIdx.x * blockDim.x + threadIdx.x) >> 6;
    int lane = threadIdx.x & 63;
    int b = wg >> 9, h = wg & 511;
    const float* wr = fc1_W + (size_t)h * 1024;
    float acc = 0.f;
    {
        float4 w0 = *(const float4*)(wr + lane * 8);
        float4 w1 = *(const float4*)(wr + lane * 8 + 4);
        float4 x0 = *(const float4*)(mc + b * Hd + lane * 8);
        float4 x1 = *(const float4*)(mc + b * Hd + lane * 8 + 4);
        acc += w0.x * x0.x + w0.y * x0.y + w0.z * x0.z + w0.w * x0.w;
        acc += w1.x * x1.x + w1.y * x1.y + w1.z * x1.z + w1.w * x1.w;
    }
    {
        float4 w0 = *(const float4*)(wr + 512 + lane * 8);
        float4 w1 = *(const float4*)(wr + 512 + lane * 8 + 4);
        float4 x0 = *(const float4*)(ctx + b * Hd + lane * 8);
        float4 x1 = *(const float4*)(ctx + b * Hd + lane * 8 + 4);
        acc += w0.x * x0.x + w0.y * x0.y + w0.z * x0.z + w0.w * x0.w;
        acc += w1.x * x1.x + w1.y * x1.y + w1.z * x1.z + w1.w * x1.w;
    }
    acc = wave_sum(acc);
    if (lane == 0) out1[b * Hd + h] = fmaxf(acc + fc1_b[h], 0.f);
}

// ---------------------------------------------------------------------------
// K6: out2[b,h] = relu( dot(out1, fc2_W[h,:]) + fc2_b[h] )   (fp32)
// ---------------------------------------------------------------------------
__global__ void fc2_kernel(const float* __restrict__ out1,
                           const float* __restrict__ fc2_W,
                           const float* __restrict__ fc2_b,
                           float* __restrict__ out2) {
    int wg = (blockIdx.x * blockDim.x + threadIdx.x) >> 6;
    int lane = threadIdx.x & 63;
    int b = wg >> 9, h = wg & 511;
    const float* wr = fc2_W + (size_t)h * 512 + lane * 8;
    float4 w0 = *(const float4*)wr;
    float4 w1 = *(const float4*)(wr + 4);
    float4 x0 = *(const float4*)(out1 + b * Hd + lane * 8);
    float4 x1 = *(const float4*)(out1 + b * Hd + lane * 8 + 4);
    float acc = w0.x * x0.x + w0.y * x0.y + w0.z * x0.z + w0.w * x0.w +
                w1.x * x1.x + w1.y * x1.y + w1.z * x1.z + w1.w * x1.w;
    acc = wave_sum(acc);
    if (lane == 0) out2[b * Hd + h] = fmaxf(acc + fc2_b[h], 0.f);
}

// ---------------------------------------------------------------------------
// K7: probs[b,n] = sum_h ptr_v[h] * tanh( sn[b][h][n] + out2[b,h] )  (fp32)
// block = (b, 256-n chunk); wave w covers h in [w*128, w*128+128).
// Per h: 64 lanes read 1KB contiguous row segment (perfect coalescing).
// ---------------------------------------------------------------------------
__global__ void final_kernel(const float* __restrict__ sn,
                             const float* __restrict__ ptr_v,
                             const float* __restrict__ out2,
                             float* __restrict__ probs) {
    int b = blockIdx.x >> 2;
    int n0 = (blockIdx.x & 3) << 8;
    int t = threadIdx.x;
    int w = t >> 6, l = t & 63;
    __shared__ float pv_s[512], o2_s[512];
    __shared__ float fsum[4][256];
    pv_s[t] = ptr_v[t];
    pv_s[t + 256] = ptr_v[t + 256];
    o2_s[t] = out2[b * Hd + t];
    o2_s[t + 256] = out2[b * Hd + t + 256];
    __syncthreads();
    const float* col = sn + (size_t)b * Hd * Nn + n0 + l * 4;
    float a0 = 0.f, a1 = 0.f, a2 = 0.f, a3 = 0.f;
#pragma unroll 4
    for (int j = 0; j < 128; ++j) {
        int h = w * 128 + j;
        float4 f = *(const float4*)&col[(size_t)h * Nn];
        float p = pv_s[h], o = o2_s[h];
        a0 += p * tanh_fast(f.x + o);
        a1 += p * tanh_fast(f.y + o);
        a2 += p * tanh_fast(f.z + o);
        a3 += p * tanh_fast(f.w + o);
    }
    fsum[w][l * 4 + 0] = a0;
    fsum[w][l * 4 + 1] = a1;
    fsum[w][l * 4 + 2] = a2;
    fsum[w][l * 4 + 3] = a3;
    __syncthreads();
    float r = fsum[0][t & 255] + fsum[1][t & 255] + fsum[2][t & 255] + fsum[3][t & 255];
    probs[b * Nn + n0 + (t & 255)] = r;
}

// ---------------------------------------------------------------------------
extern "C" void kernel_launch(void* const* d_in, const int* in_sizes, int n_in,
                              void* d_out, int out_size, void* d_ws, size_t ws_size,
                              hipStream_t stream) {
    const float* mc  = (const float*)d_in[0];
    const float* sn  = (const float*)d_in[1];
    const float* aW  = (const float*)d_in[2];
    const float* av  = (const float*)d_in[3];
    const float* pv  = (const float*)d_in[4];
    const float* f1W = (const float*)d_in[5];
    const float* f1b = (const float*)d_in[6];
    const float* f2W = (const float*)d_in[7];
    const float* f2b = (const float*)d_in[8];

    unsigned short* Wb = (unsigned short*)d_ws;             // 512 KB
    float* fws         = (float*)(Wb + 512 * 512);
    float* mc_term     = fws;                               // 256 KB
    float* scores_part = mc_term + Bn * Hd;                 // 2 x 512 KB
    float* attns       = scores_part + 2 * Bn * Nn;         // 512 KB
    float* context     = attns + Bn * Nn;                   // 256 KB
    float* out1        = context + Bn * Hd;
    float* out2        = out1 + Bn * Hd;
    float* probs       = (float*)d_out;

    pre_kernel<<<dim3(16512), dim3(256), 0, stream>>>(aW, mc, Wb, mc_term);
    attn_score_kernel<<<dim3(2048), dim3(256), 0, stream>>>(sn, Wb, av, mc_term, scores_part);
    softmax_kernel<<<dim3(128), dim3(256), 0, stream>>>(scores_part, attns);
    context_kernel<<<dim3(1024), dim3(256), 0, stream>>>(sn, attns, context);
    fc1_kernel<<<dim3(16384), dim3(256), 0, stream>>>(mc, context, f1W, f1b, out1);
    fc2_kernel<<<dim3(16384), dim3(256), 0, stream>>>(out1, f2W, f2b, out2);
    final_kernel<<<dim3(512), dim3(256), 0, stream>>>(sn, pv, out2, probs);
}

// Round 4
// 524.690 us; speedup vs baseline: 1.0782x; 1.0050x over previous
//
#include <hip/hip_runtime.h>
#include <hip/hip_bf16.h>

#define Bn 128
#define Hd 512
#define Nn 1024

typedef __attribute__((ext_vector_type(8))) short short8;
typedef __attribute__((ext_vector_type(4))) float f32x4;

#define GLOAD_LDS16(gptr, lptr)                                                     \
    __builtin_amdgcn_global_load_lds(                                               \
        (const __attribute__((address_space(1))) void*)(gptr),                      \
        (__attribute__((address_space(3))) void*)(lptr), 16, 0, 0)

// packed RNE f32x2 -> bf16x2 (compiler emits v_cvt_pk_bf16_f32)
__device__ __forceinline__ unsigned pack_bf2(float a, float b) {
    __hip_bfloat162 h = __float22bfloat162_rn(float2{a, b});
    unsigned u;
    __builtin_memcpy(&u, &h, 4);
    return u;
}

__device__ __forceinline__ float wave_sum(float v) {
    v += __shfl_xor(v, 32);
    v += __shfl_xor(v, 16);
    v += __shfl_xor(v, 8);
    v += __shfl_xor(v, 4);
    v += __shfl_xor(v, 2);
    v += __shfl_xor(v, 1);
    return v;
}

__device__ __forceinline__ float tanh_fast(float x) {
    float e = __expf(2.0f * x);
    return 1.0f - 2.0f * __builtin_amdgcn_rcpf(e + 1.0f);
}

// ---------------------------------------------------------------------------
// K0: fused preprocessing.
//   blocks [0,128):    Wb[h][k] = bf16(attn_W[h][k]), k in [0,512)
//   blocks [128,16512): mc_term[b,h] = sum_k attn_W[h,512+k]*mc[b,k]  (fp32)
// ---------------------------------------------------------------------------
__global__ void pre_kernel(const float* __restrict__ attn_W,
                           const float* __restrict__ mc,
                           unsigned short* __restrict__ Wb,
                           float* __restrict__ mc_term) {
    if (blockIdx.x < 128) {
        int idx = (blockIdx.x * 256 + threadIdx.x) * 8;
        int h = idx >> 9;
        int k = idx & 511;
        const float* p = attn_W + (size_t)h * 1024 + k;
        float4 v0 = *(const float4*)p;
        float4 v1 = *(const float4*)(p + 4);
        unsigned u[4] = {pack_bf2(v0.x, v0.y), pack_bf2(v0.z, v0.w),
                         pack_bf2(v1.x, v1.y), pack_bf2(v1.z, v1.w)};
        *(uint4*)(Wb + idx) = *(uint4*)u;
        return;
    }
    int wg = ((blockIdx.x - 128) * 256 + threadIdx.x) >> 6;
    int lane = threadIdx.x & 63;
    int b = wg >> 9;
    int h = wg & 511;
    const float* m = mc + b * Hd + lane * 8;
    const float* w = attn_W + (size_t)h * 1024 + 512 + lane * 8;
    float4 m0 = *(const float4*)m, m1 = *(const float4*)(m + 4);
    float4 w0 = *(const float4*)w, w1 = *(const float4*)(w + 4);
    float acc = m0.x * w0.x + m0.y * w0.y + m0.z * w0.z + m0.w * w0.w +
                m1.x * w1.x + m1.y * w1.y + m1.z * w1.z + m1.w * w1.w;
    acc = wave_sum(acc);
    if (lane == 0) mc_term[b * Hd + h] = acc;
}

// ---------------------------------------------------------------------------
// K2: scores_part[mh][b][n] -- MFMA GEMM, fused in-kernel B transpose.
// BM=256 x BN=128 x BK=64, 4 waves; wave w owns m [w*64,w*64+64), all 128 n.
// A: bf16 Wb via global_load_lds (chunk-XOR swizzle, proven layout).
// B: staged FRAGMENT-READY: [n][k] bf16 rows, 16B chunk c of row n at byte
//    n*128 + ((c^(n&7))*16). Stage = 8 coalesced dword loads per (n,c) +
//    cvt_pk x4 + ONE ds_write_b128. Frag reads = ds_read_b128, slot-XOR
//    matched to store (bank-optimal 8 lanes/slot). Kills the b32 gather
//    (was ~2900 cyc/CU/K-step vs 620 MFMA).
// ---------------------------------------------------------------------------
__global__ __launch_bounds__(256, 2)
void attn_score_kernel(const float* __restrict__ sn,
                       const unsigned short* __restrict__ Wb,
                       const float* __restrict__ attn_v,
                       const float* __restrict__ mc_term,
                       float* __restrict__ scores_part) {
    __shared__ __align__(16) unsigned short A_lds[256 * 64];  // [m][k] 32KB
    __shared__ __align__(16) unsigned short B_lds[128 * 64];  // [n][k] 16KB
    __shared__ float av_s[256];
    __shared__ float mct_s[256];
    __shared__ float ssum[128];

    const int bid = blockIdx.x;
    const int b = bid >> 4;
    const int mh = (bid >> 3) & 1;        // m-half: rows [mh*256, mh*256+256)
    const int n0 = (bid & 7) << 7;        // 128-wide n tile
    const int tid = threadIdx.x;
    const int lane = tid & 63;
    const int wid = tid >> 6;
    const int quad = lane >> 4;
    const int l15 = lane & 15;

    av_s[tid] = attn_v[mh * 256 + tid];
    mct_s[tid] = mc_term[b * Hd + mh * 256 + tid];
    if (tid < 128) ssum[tid] = 0.f;

    f32x4 acc[4][8];
#pragma unroll
    for (int i = 0; i < 4; ++i)
#pragma unroll
        for (int j = 0; j < 8; ++j) {
            f32x4 z = {0.f, 0.f, 0.f, 0.f};
            acc[i][j] = z;
        }

    const int r8 = lane >> 3;                  // A-staging row within 8-group
    const int csw = ((lane & 7) ^ r8) * 16;    // A swizzled chunk byte offset
    const char* Wg = (const char*)Wb + (size_t)(mh * 256) * 1024;
    const int key = l15 & 7;

    // B staging map: thread -> k-chunk cB (8 rows), n-column nbB (+32j)
    const int cB = tid >> 5;                   // 0..7
    const int nbB = tid & 31;                  // 0..31
    const int bswz = ((cB ^ (nbB & 7)) * 16);  // loop-invariant chunk slot
    const float* snB = sn + (size_t)b * Hd * Nn + n0 + nbB + (size_t)(8 * cB) * Nn;

    for (int k0 = 0; k0 < 512; k0 += 64) {
        // stage A: wave's 64 m-rows, 8 global_load_lds x 1KB
#pragma unroll
        for (int i = 0; i < 8; ++i) {
            const int row = wid * 64 + i * 8;
            GLOAD_LDS16(Wg + (size_t)(row + r8) * 1024 + k0 * 2 + csw,
                        (char*)A_lds + row * 128);
        }
        // stage B: per (n, cB): 8 k-rows (coalesced dwords) -> 1 b128 write
        {
            const float* pk = snB + (size_t)k0 * Nn;
#pragma unroll
            for (int j = 0; j < 4; ++j) {
                const int n = nbB + 32 * j;
                const float* p = pk + 32 * j;
                float v0 = p[0 * Nn], v1 = p[1 * Nn], v2 = p[2 * Nn], v3 = p[3 * Nn];
                float v4 = p[4 * Nn], v5 = p[5 * Nn], v6 = p[6 * Nn], v7 = p[7 * Nn];
                unsigned kp[4] = {pack_bf2(v0, v1), pack_bf2(v2, v3),
                                  pack_bf2(v4, v5), pack_bf2(v6, v7)};
                *(uint4*)((char*)B_lds + n * 128 + bswz) = *(uint4*)kp;
            }
        }
        __syncthreads();
#pragma unroll
        for (int kk = 0; kk < 2; ++kk) {
            const int cb = quad + kk * 4;      // k-chunk: k_local = cb*8..+8
            short8 bfr[8], afr[4];
#pragma unroll
            for (int nt = 0; nt < 8; ++nt) {
                const int nl = nt * 16 + l15;
                bfr[nt] = *(const short8*)((const char*)B_lds + nl * 128 + ((cb ^ key) * 16));
            }
#pragma unroll
            for (int mt = 0; mt < 4; ++mt) {
                const int m = wid * 64 + mt * 16 + l15;
                afr[mt] = *(const short8*)((const char*)A_lds + m * 128 + ((cb ^ key) * 16));
            }
#pragma unroll
            for (int mt = 0; mt < 4; ++mt)
#pragma unroll
                for (int nt = 0; nt < 8; ++nt)
                    acc[mt][nt] = __builtin_amdgcn_mfma_f32_16x16x32_bf16(afr[mt], bfr[nt], acc[mt][nt], 0, 0, 0);
        }
        __syncthreads();
    }

    // epilogue: tanh + attn_v dot over this block's 256 h, reduce, store part
    float s[8] = {0.f, 0.f, 0.f, 0.f, 0.f, 0.f, 0.f, 0.f};
#pragma unroll
    for (int mt = 0; mt < 4; ++mt) {
        int hb = wid * 64 + mt * 16 + quad * 4;
#pragma unroll
        for (int r = 0; r < 4; ++r) {
            float av = av_s[hb + r];
            float mcv = mct_s[hb + r];
#pragma unroll
            for (int nt = 0; nt < 8; ++nt)
                s[nt] += av * tanh_fast(acc[mt][nt][r] + mcv);
        }
    }
#pragma unroll
    for (int nt = 0; nt < 8; ++nt) {
        float v = s[nt];
        v += __shfl_xor(v, 16);
        v += __shfl_xor(v, 32);
        if (lane < 16) atomicAdd(&ssum[nt * 16 + l15], v);
    }
    __syncthreads();
    if (tid < 128)
        scores_part[((size_t)mh * Bn + b) * Nn + n0 + tid] = ssum[tid];
}

// ---------------------------------------------------------------------------
// K3+K4 fused: softmax stats recomputed per block (8 KB redundant read),
// then context[b,h] = sum_n attns[b,n] * sn[b][h][n]   (fp32, no atomics)
// block = (b, 64 h). thread: h = h0 + t>>2, n-phase q = t&3.
// ---------------------------------------------------------------------------
__global__ void softmax_context_kernel(const float* __restrict__ sn,
                                       const float* __restrict__ scores_part,
                                       float* __restrict__ context) {
    int b = blockIdx.x >> 3;
    int h0 = (blockIdx.x & 7) << 6;
    int t = threadIdx.x;
    int lane = t & 63, wid = t >> 6;
    __shared__ float red[4];
    __shared__ float a_s[1024];

    const float* s0 = scores_part + (size_t)b * Nn;
    const float* s1 = scores_part + ((size_t)Bn + b) * Nn;
    float v[4];
#pragma unroll
    for (int i = 0; i < 4; ++i) {
        int idx = t + i * 256;
        v[i] = s0[idx] + s1[idx];
    }
    float m = fmaxf(fmaxf(v[0], v[1]), fmaxf(v[2], v[3]));
#pragma unroll
    for (int off = 32; off >= 1; off >>= 1) m = fmaxf(m, __shfl_xor(m, off));
    if (lane == 0) red[wid] = m;
    __syncthreads();
    m = fmaxf(fmaxf(red[0], red[1]), fmaxf(red[2], red[3]));
    __syncthreads();
    float s = 0.f;
#pragma unroll
    for (int i = 0; i < 4; ++i) {
        v[i] = __expf(v[i] - m);
        s += v[i];
    }
    s = wave_sum(s);
    if (lane == 0) red[wid] = s;
    __syncthreads();
    s = red[0] + red[1] + red[2] + red[3];
    float inv = __builtin_amdgcn_rcpf(s);
#pragma unroll
    for (int i = 0; i < 4; ++i) a_s[t + i * 256] = v[i] * inv;
    __syncthreads();

    int h = h0 + (t >> 2), q = t & 3;
    const float* row = sn + ((size_t)b * Hd + h) * Nn;
    float acc = 0.f;
#pragma unroll 8
    for (int j = 0; j < 64; ++j) {
        int n = q * 4 + j * 16;
        float4 f = *(const float4*)&row[n];
        float4 a = *(const float4*)&a_s[n];
        acc += f.x * a.x + f.y * a.y + f.z * a.z + f.w * a.w;
    }
    acc += __shfl_xor(acc, 1);
    acc += __shfl_xor(acc, 2);
    if (q == 0) context[b * Hd + h] = acc;
}

// ---------------------------------------------------------------------------
// K5: out1[b,h] = relu( dot([mc|context], fc1_W[h,:]) + fc1_b[h] )   (fp32)
// ---------------------------------------------------------------------------
__global__ void fc1_kernel(const float* __restrict__ mc,
                           const float* __restrict__ ctx,
                           const float* __restrict__ fc1_W,
                           const float* __restrict__ fc1_b,
                           float* __restrict__ out1) {
    int wg = (blockIdx.x * blockDim.x + threadIdx.x) >> 6;
    int lane = threadIdx.x & 63;
    int b = wg >> 9, h = wg & 511;
    const float* wr = fc1_W + (size_t)h * 1024;
    float acc = 0.f;
    {
        float4 w0 = *(const float4*)(wr + lane * 8);
        float4 w1 = *(const float4*)(wr + lane * 8 + 4);
        float4 x0 = *(const float4*)(mc + b * Hd + lane * 8);
        float4 x1 = *(const float4*)(mc + b * Hd + lane * 8 + 4);
        acc += w0.x * x0.x + w0.y * x0.y + w0.z * x0.z + w0.w * x0.w;
        acc += w1.x * x1.x + w1.y * x1.y + w1.z * x1.z + w1.w * x1.w;
    }
    {
        float4 w0 = *(const float4*)(wr + 512 + lane * 8);
        float4 w1 = *(const float4*)(wr + 512 + lane * 8 + 4);
        float4 x0 = *(const float4*)(ctx + b * Hd + lane * 8);
        float4 x1 = *(const float4*)(ctx + b * Hd + lane * 8 + 4);
        acc += w0.x * x0.x + w0.y * x0.y + w0.z * x0.z + w0.w * x0.w;
        acc += w1.x * x1.x + w1.y * x1.y + w1.z * x1.z + w1.w * x1.w;
    }
    acc = wave_sum(acc);
    if (lane == 0) out1[b * Hd + h] = fmaxf(acc + fc1_b[h], 0.f);
}

// ---------------------------------------------------------------------------
// K6: out2[b,h] = relu( dot(out1, fc2_W[h,:]) + fc2_b[h] )   (fp32)
// ---------------------------------------------------------------------------
__global__ void fc2_kernel(const float* __restrict__ out1,
                           const float* __restrict__ fc2_W,
                           const float* __restrict__ fc2_b,
                           float* __restrict__ out2) {
    int wg = (blockIdx.x * blockDim.x + threadIdx.x) >> 6;
    int lane = threadIdx.x & 63;
    int b = wg >> 9, h = wg & 511;
    const float* wr = fc2_W + (size_t)h * 512 + lane * 8;
    float4 w0 = *(const float4*)wr;
    float4 w1 = *(const float4*)(wr + 4);
    float4 x0 = *(const float4*)(out1 + b * Hd + lane * 8);
    float4 x1 = *(const float4*)(out1 + b * Hd + lane * 8 + 4);
    float acc = w0.x * x0.x + w0.y * x0.y + w0.z * x0.z + w0.w * x0.w +
                w1.x * x1.x + w1.y * x1.y + w1.z * x1.z + w1.w * x1.w;
    acc = wave_sum(acc);
    if (lane == 0) out2[b * Hd + h] = fmaxf(acc + fc2_b[h], 0.f);
}

// ---------------------------------------------------------------------------
// K7: probs[b,n] = sum_h ptr_v[h] * tanh( sn[b][h][n] + out2[b,h] )  (fp32)
// block = (b, 256-n chunk); wave w covers h in [w*128, w*128+128).
// ---------------------------------------------------------------------------
__global__ void final_kernel(const float* __restrict__ sn,
                             const float* __restrict__ ptr_v,
                             const float* __restrict__ out2,
                             float* __restrict__ probs) {
    int b = blockIdx.x >> 2;
    int n0 = (blockIdx.x & 3) << 8;
    int t = threadIdx.x;
    int w = t >> 6, l = t & 63;
    __shared__ float pv_s[512], o2_s[512];
    __shared__ float fsum[4][256];
    pv_s[t] = ptr_v[t];
    pv_s[t + 256] = ptr_v[t + 256];
    o2_s[t] = out2[b * Hd + t];
    o2_s[t + 256] = out2[b * Hd + t + 256];
    __syncthreads();
    const float* col = sn + (size_t)b * Hd * Nn + n0 + l * 4;
    float a0 = 0.f, a1 = 0.f, a2 = 0.f, a3 = 0.f;
#pragma unroll 4
    for (int j = 0; j < 128; ++j) {
        int h = w * 128 + j;
        float4 f = *(const float4*)&col[(size_t)h * Nn];
        float p = pv_s[h], o = o2_s[h];
        a0 += p * tanh_fast(f.x + o);
        a1 += p * tanh_fast(f.y + o);
        a2 += p * tanh_fast(f.z + o);
        a3 += p * tanh_fast(f.w + o);
    }
    fsum[w][l * 4 + 0] = a0;
    fsum[w][l * 4 + 1] = a1;
    fsum[w][l * 4 + 2] = a2;
    fsum[w][l * 4 + 3] = a3;
    __syncthreads();
    float r = fsum[0][t & 255] + fsum[1][t & 255] + fsum[2][t & 255] + fsum[3][t & 255];
    probs[b * Nn + n0 + (t & 255)] = r;
}

// ---------------------------------------------------------------------------
extern "C" void kernel_launch(void* const* d_in, const int* in_sizes, int n_in,
                              void* d_out, int out_size, void* d_ws, size_t ws_size,
                              hipStream_t stream) {
    const float* mc  = (const float*)d_in[0];
    const float* sn  = (const float*)d_in[1];
    const float* aW  = (const float*)d_in[2];
    const float* av  = (const float*)d_in[3];
    const float* pv  = (const float*)d_in[4];
    const float* f1W = (const float*)d_in[5];
    const float* f1b = (const float*)d_in[6];
    const float* f2W = (const float*)d_in[7];
    const float* f2b = (const float*)d_in[8];

    unsigned short* Wb = (unsigned short*)d_ws;             // 512 KB
    float* fws         = (float*)(Wb + 512 * 512);
    float* mc_term     = fws;                               // 256 KB
    float* scores_part = mc_term + Bn * Hd;                 // 2 x 512 KB
    float* context     = scores_part + 2 * Bn * Nn;         // 256 KB
    float* out1        = context + Bn * Hd;
    float* out2        = out1 + Bn * Hd;
    float* probs       = (float*)d_out;

    pre_kernel<<<dim3(16512), dim3(256), 0, stream>>>(aW, mc, Wb, mc_term);
    attn_score_kernel<<<dim3(2048), dim3(256), 0, stream>>>(sn, Wb, av, mc_term, scores_part);
    softmax_context_kernel<<<dim3(1024), dim3(256), 0, stream>>>(sn, scores_part, context);
    fc1_kernel<<<dim3(16384), dim3(256), 0, stream>>>(mc, context, f1W, f1b, out1);
    fc2_kernel<<<dim3(16384), dim3(256), 0, stream>>>(out1, f2W, f2b, out2);
    final_kernel<<<dim3(512), dim3(256), 0, stream>>>(sn, pv, out2, probs);
}